// Round 1
// baseline (764.499 us; speedup 1.0000x reference)
//
#include <hip/hip_runtime.h>
#include <hip/hip_bf16.h>

// GAT layer, B=8 N=4096 F=128 U=64, ALL I/O float32.
// out = relu( softmax_row( lrelu(s_i + t_j) masked by A ) @ X ),  X = H@W.
// A (512 MB f32) is the only O(N^2) tensor. R5: A's 2D row-tile access in
// attn was latency/request-bound (~1.7 TB/s). Split the stream from the
// compute: a sequential-pattern compress pass (lane-contiguous f32x4 reads,
// ~6.3 TB/s) turns A into a 134 MB byte mask (LLC-resident); attn decodes
// bytes via v_cvt_f32_ubyte. Compress is fused into the prep launch as a
// block-role split so the two overlap.

#define NTOK 4096
#define FDIM 128
#define UDIM 64
#define BATCH 8

typedef __attribute__((ext_vector_type(8))) short short8;
typedef __attribute__((ext_vector_type(4))) float f32x4;

union PackU { unsigned u[4]; short8 s; };

// round-to-nearest-even f32 -> bf16 (used in prep only)
__device__ __forceinline__ unsigned short f2bf(float x) {
    unsigned u = __float_as_uint(x);
    return (unsigned short)((u + 0x7fffu + ((u >> 16) & 1u)) >> 16);
}

// ---------------- kernel 1: role split ------------------------------------
// blocks 0..511:    X = H@W (MFMA), s,t (pre-scaled by log2e), XT bf16
// blocks 512..2559: compress A f32 -> byte mask (0/1), fully sequential
#define PREP_BLOCKS 512
#define CMP_BLOCKS 2048
__global__ __launch_bounds__(256) void prep_kernel(
    const float* __restrict__ H,    // f32 [B*N, 128]
    const float* __restrict__ W,    // f32 [128, 64]
    const float* __restrict__ a1,   // f32 [64]
    const float* __restrict__ a2,   // f32 [64]
    const float* __restrict__ A,    // f32 [B, N, N] -- 512 MB stream
    unsigned short* __restrict__ XT,// bf16 [B, 64, N] (scratch)
    float* __restrict__ s_out,      // f32 [B*N], = (X@a1)*log2(e)
    float* __restrict__ t_out,      // f32 [B*N], = (X@a2)*log2(e)
    unsigned char* __restrict__ AM) // u8 [B, N, N] mask (scratch, 128 MB)
{
    __shared__ float Xl[4][16][UDIM + 1];

    if (blockIdx.x >= PREP_BLOCKS) {
        // ---- compress role: 2048 blocks, 64 slabs of 2 MB words ----
        const size_t tidg = (size_t)(blockIdx.x - PREP_BLOCKS) * 256 + threadIdx.x;
        const size_t STR  = (size_t)CMP_BLOCKS * 256;           // 524288 threads
        const f32x4* av = (const f32x4*)A;
        unsigned* mw = (unsigned*)AM;
        // total words = B*N*N/4 = 33,554,432 = 64 * STR
        #pragma unroll 1
        for (int it = 0; it < 32; ++it) {
            size_t w0 = tidg + (size_t)(2 * it) * STR;
            size_t w1 = w0 + STR;
            f32x4 v0 = __builtin_nontemporal_load(av + w0);
            f32x4 v1 = __builtin_nontemporal_load(av + w1);
            unsigned m0 = (v0[0] != 0.f ? 1u : 0u)
                        | (v0[1] != 0.f ? 1u << 8 : 0u)
                        | (v0[2] != 0.f ? 1u << 16 : 0u)
                        | (v0[3] != 0.f ? 1u << 24 : 0u);
            unsigned m1 = (v1[0] != 0.f ? 1u : 0u)
                        | (v1[1] != 0.f ? 1u << 8 : 0u)
                        | (v1[2] != 0.f ? 1u << 16 : 0u)
                        | (v1[3] != 0.f ? 1u << 24 : 0u);
            mw[w0] = m0;    // plain store: keep LLC-resident for attn
            mw[w1] = m1;
        }
        return;
    }

    // ---- prep role (unchanged from R4) ----
    const int tid  = threadIdx.x;
    const int wave = tid >> 6, lane = tid & 63;
    const int col  = lane & 15, quad = lane >> 4;
    const int i0   = (blockIdx.x * 4 + wave) * 16;

    f32x4 acc0 = {0,0,0,0}, acc1 = {0,0,0,0}, acc2 = {0,0,0,0}, acc3 = {0,0,0,0};
    const float* hrow = H + (size_t)(i0 + col) * FDIM + quad * 8;

    #pragma unroll
    for (int kb = 0; kb < FDIM; kb += 32) {
        f32x4 h0 = *(const f32x4*)(hrow + kb);       // A[m=lane&15][k=quad*8+j]
        f32x4 h1 = *(const f32x4*)(hrow + kb + 4);
        short8 afr, b0, b1, b2, b3;
        #pragma unroll
        for (int j = 0; j < 4; ++j) {
            afr[j]     = (short)f2bf(h0[j]);
            afr[4 + j] = (short)f2bf(h1[j]);
        }
        #pragma unroll
        for (int j = 0; j < 8; ++j) {                // W tiny, L1-hot
            int k = kb + quad * 8 + j;
            b0[j] = (short)f2bf(W[k * UDIM + col]);
            b1[j] = (short)f2bf(W[k * UDIM + 16 + col]);
            b2[j] = (short)f2bf(W[k * UDIM + 32 + col]);
            b3[j] = (short)f2bf(W[k * UDIM + 48 + col]);
        }
        acc0 = __builtin_amdgcn_mfma_f32_16x16x32_bf16(afr, b0, acc0, 0, 0, 0);
        acc1 = __builtin_amdgcn_mfma_f32_16x16x32_bf16(afr, b1, acc1, 0, 0, 0);
        acc2 = __builtin_amdgcn_mfma_f32_16x16x32_bf16(afr, b2, acc2, 0, 0, 0);
        acc3 = __builtin_amdgcn_mfma_f32_16x16x32_bf16(afr, b3, acc3, 0, 0, 0);
    }
    #pragma unroll
    for (int r = 0; r < 4; ++r) {   // C/D: col(u)=lane&15 (+16/group), row=quad*4+r
        Xl[wave][quad * 4 + r][col]      = acc0[r];
        Xl[wave][quad * 4 + r][16 + col] = acc1[r];
        Xl[wave][quad * 4 + r][32 + col] = acc2[r];
        Xl[wave][quad * 4 + r][48 + col] = acc3[r];
    }
    __syncthreads();

    const int b = i0 >> 12, n0 = i0 & (NTOK - 1);
    float ps = 0.f, pt = 0.f;
    #pragma unroll
    for (int ui = 0; ui < 16; ++ui) {
        int u = quad * 16 + ui;
        float x = Xl[wave][col][u];
        ps = fmaf(x, a1[u], ps);
        pt = fmaf(x, a2[u], pt);
    }
    ps += __shfl_xor(ps, 16, 64); ps += __shfl_xor(ps, 32, 64);
    pt += __shfl_xor(pt, 16, 64); pt += __shfl_xor(pt, 32, 64);
    const float LOG2E = 1.44269504f;
    if (quad == 0) s_out[i0 + col] = ps * LOG2E;   // exp2 domain
    if (quad == 1) t_out[i0 + col] = pt * LOG2E;

    #pragma unroll
    for (int ui = 0; ui < 16; ++ui) {
        int u = quad * 16 + ui;
        XT[(size_t)(b * UDIM + u) * NTOK + n0 + col] = f2bf(Xl[wave][col][u]);
    }
}

// ---------------- kernel 2: fused mask+softmax+PV ---------------------------
// grid 512 = 8 batches x 64 row-tiles-of-64 (b = bx&7), 4 waves/block.
// Each wave: 4 row-groups of 16 x its K-chunk of 1024, step 32.
// A now arrives as a byte mask (8 B/lane/group instead of 32 B) from LLC.
__global__ __launch_bounds__(256) void attn_kernel(
    const unsigned char* __restrict__ AM,   // u8 [B, N, N] mask
    const unsigned short* __restrict__ XT,  // bf16 [B, 64, N]
    const float* __restrict__ s_in,         // log2e-scaled
    const float* __restrict__ t_in,         // log2e-scaled
    float* __restrict__ out)                // f32 [B, N, 64]
{
    __shared__ float part[4][64][UDIM + 1]; // 66.6 KB: per-wave partial numerators
    __shared__ float denl[4][64];

    const int tid  = threadIdx.x;
    const int wave = tid >> 6, lane = tid & 63;
    const int bx   = blockIdx.x;
    const int b    = bx & 7;
    const int i0   = (bx >> 3) * 64;
    const int col  = lane & 15, quad = lane >> 4;
    const int kstart = wave * (NTOK / 4);

    float s_m[4];
    #pragma unroll
    for (int g = 0; g < 4; ++g) s_m[g] = s_in[b * NTOK + i0 + g * 16 + col];

    const unsigned char* mp[4];
    #pragma unroll
    for (int g = 0; g < 4; ++g)
        mp[g] = AM + ((size_t)(b * NTOK + i0 + g * 16 + col)) * NTOK + kstart + quad * 8;
    const float* tptr = t_in + b * NTOK + kstart + quad * 8;
    const unsigned short* xb  = XT + (size_t)b * UDIM * NTOK + kstart + quad * 8;
    const unsigned short* xp0 = xb + (size_t)(col)      * NTOK;
    const unsigned short* xp1 = xb + (size_t)(16 + col) * NTOK;
    const unsigned short* xp2 = xb + (size_t)(32 + col) * NTOK;
    const unsigned short* xp3 = xb + (size_t)(48 + col) * NTOK;

    f32x4 acc[4][4];
    #pragma unroll
    for (int g = 0; g < 4; ++g)
        #pragma unroll
        for (int f = 0; f < 4; ++f) acc[g][f] = (f32x4){0,0,0,0};
    float den[4] = {0.f, 0.f, 0.f, 0.f};

    #pragma unroll 2
    for (int step = 0; step < 32; ++step) {
        short8 bf0 = *(const short8*)xp0;          // shared across row-groups
        short8 bf1 = *(const short8*)xp1;
        short8 bf2 = *(const short8*)xp2;
        short8 bf3 = *(const short8*)xp3;
        f32x4 t0  = *(const f32x4*)tptr;           // k = quad*8 + 0..3
        f32x4 t1  = *(const f32x4*)(tptr + 4);     // k = quad*8 + 4..7

        #pragma unroll
        for (int g = 0; g < 4; ++g) {
            uint2 mv = *(const uint2*)mp[g];       // 8 mask bytes, k = quad*8+0..7
            unsigned uw[8];
            #pragma unroll
            for (int j = 0; j < 4; ++j) {
                float am0 = (float)((mv.x >> (8 * j)) & 0xffu);  // v_cvt_f32_ubyteN
                float am1 = (float)((mv.y >> (8 * j)) & 0xffu);
                float l0 = s_m[g] + t0[j], l1 = s_m[g] + t1[j];
                float e0 = fmaxf(l0, 0.2f * l0);   // lrelu commutes with log2e>0
                float e1 = fmaxf(l1, 0.2f * l1);
                float w0 = __builtin_amdgcn_exp2f(e0) * am0;  // masked -> exact 0
                float w1 = __builtin_amdgcn_exp2f(e1) * am1;
                den[g] += w0 + w1;
                uw[j]     = __float_as_uint(w0) + 0x8000u;  // round-half-up bf16
                uw[4 + j] = __float_as_uint(w1) + 0x8000u;
            }
            PackU p;   // pack hi16 pairs: afr[k]=w(k), k=quad*8+j
            p.u[0] = __builtin_amdgcn_perm(uw[1], uw[0], 0x07060302u);
            p.u[1] = __builtin_amdgcn_perm(uw[3], uw[2], 0x07060302u);
            p.u[2] = __builtin_amdgcn_perm(uw[5], uw[4], 0x07060302u);
            p.u[3] = __builtin_amdgcn_perm(uw[7], uw[6], 0x07060302u);

            acc[g][0] = __builtin_amdgcn_mfma_f32_16x16x32_bf16(p.s, bf0, acc[g][0], 0, 0, 0);
            acc[g][1] = __builtin_amdgcn_mfma_f32_16x16x32_bf16(p.s, bf1, acc[g][1], 0, 0, 0);
            acc[g][2] = __builtin_amdgcn_mfma_f32_16x16x32_bf16(p.s, bf2, acc[g][2], 0, 0, 0);
            acc[g][3] = __builtin_amdgcn_mfma_f32_16x16x32_bf16(p.s, bf3, acc[g][3], 0, 0, 0);
            mp[g] += 32;
        }
        tptr += 32; xp0 += 32; xp1 += 32; xp2 += 32; xp3 += 32;
    }

    #pragma unroll
    for (int g = 0; g < 4; ++g) {
        den[g] += __shfl_xor(den[g], 16, 64);
        den[g] += __shfl_xor(den[g], 32, 64);
        if (quad == 0) denl[wave][g * 16 + col] = den[g];
        #pragma unroll
        for (int r = 0; r < 4; ++r) {
            part[wave][g * 16 + quad * 4 + r][col]      = acc[g][0][r];
            part[wave][g * 16 + quad * 4 + r][16 + col] = acc[g][1][r];
            part[wave][g * 16 + quad * 4 + r][32 + col] = acc[g][2][r];
            part[wave][g * 16 + quad * 4 + r][48 + col] = acc[g][3][r];
        }
    }
    __syncthreads();

    // cross-wave reduce + divide + relu + store (64 rows x 64 u, coalesced)
    #pragma unroll
    for (int rep = 0; rep < 16; ++rep) {
        int e = rep * 256 + tid;
        int r = e >> 6, u = e & 63;
        float num = part[0][r][u] + part[1][r][u] + part[2][r][u] + part[3][r][u];
        float dd  = denl[0][r] + denl[1][r] + denl[2][r] + denl[3][r];
        float o   = fmaxf(num / dd, 0.f);
        __builtin_nontemporal_store(o, &out[(size_t)(b * NTOK + i0 + r) * UDIM + u]);
    }
}

extern "C" void kernel_launch(void* const* d_in, const int* in_sizes, int n_in,
                              void* d_out, int out_size, void* d_ws, size_t ws_size,
                              hipStream_t stream) {
    const float* H  = (const float*)d_in[0];
    const float* A  = (const float*)d_in[1];
    const float* W  = (const float*)d_in[2];
    const float* a1 = (const float*)d_in[3];
    const float* a2 = (const float*)d_in[4];
    float* out = (float*)d_out;

    char* ws = (char*)d_ws;
    unsigned short* XT = (unsigned short*)ws;                               // 4 MB bf16
    size_t off = (size_t)BATCH * UDIM * NTOK * 2;
    float* s = (float*)(ws + off);                                          // 128 KB
    off += (size_t)BATCH * NTOK * 4;
    float* t = (float*)(ws + off);                                          // 128 KB
    off += (size_t)BATCH * NTOK * 4;
    unsigned char* AM = (unsigned char*)(ws + off);                         // 128 MB mask

    prep_kernel<<<PREP_BLOCKS + CMP_BLOCKS, 256, 0, stream>>>(H, W, a1, a2, A, XT, s, t, AM);
    attn_kernel<<<512, 256, 0, stream>>>(AM, XT, s, t, out);
}

// Round 2
// 707.399 us; speedup vs baseline: 1.0807x; 1.0807x over previous
//
#include <hip/hip_runtime.h>
#include <hip/hip_bf16.h>

// GAT layer, B=8 N=4096 F=128 U=64, ALL I/O float32.
// out = relu( softmax_row( lrelu(s_i + t_j) masked by A ) @ X ),  X = H@W.
// R6: drop the R5 compress pass (cost ~= its savings; attn is pattern-bound,
// not byte-bound). Restructure attn: waves own 16 ROWS x full K (no cross-wave
// part[] reduction), A and XT staged through double-buffered LDS with
// fully-coalesced loads (4x256B contiguous segments per wave-instr vs 16x64B
// scattered direct reads). One barrier per 64-k chunk; global loads for chunk
// c+1 issue before the barrier and land during chunk c's compute.

#define NTOK 4096
#define FDIM 128
#define UDIM 64
#define BATCH 8
#define BK 64          // k-chunk staged per barrier (2 MFMA k-steps)

typedef __attribute__((ext_vector_type(8))) short short8;
typedef __attribute__((ext_vector_type(4))) float f32x4;

union PackU { unsigned u[4]; short8 s; };

// round-to-nearest-even f32 -> bf16 (used in prep only)
__device__ __forceinline__ unsigned short f2bf(float x) {
    unsigned u = __float_as_uint(x);
    return (unsigned short)((u + 0x7fffu + ((u >> 16) & 1u)) >> 16);
}

// ---------------- kernel 1: X = H@W (MFMA), s,t (pre-scaled by log2e) ------
__global__ __launch_bounds__(256) void prep_kernel(
    const float* __restrict__ H,    // f32 [B*N, 128]
    const float* __restrict__ W,    // f32 [128, 64]
    const float* __restrict__ a1,   // f32 [64]
    const float* __restrict__ a2,   // f32 [64]
    unsigned short* __restrict__ XT,// bf16 [B, 64, N] (scratch)
    float* __restrict__ s_out,      // f32 [B*N], = (X@a1)*log2(e)
    float* __restrict__ t_out)      // f32 [B*N], = (X@a2)*log2(e)
{
    __shared__ float Xl[4][16][UDIM + 1];

    const int tid  = threadIdx.x;
    const int wave = tid >> 6, lane = tid & 63;
    const int col  = lane & 15, quad = lane >> 4;
    const int i0   = (blockIdx.x * 4 + wave) * 16;

    f32x4 acc0 = {0,0,0,0}, acc1 = {0,0,0,0}, acc2 = {0,0,0,0}, acc3 = {0,0,0,0};
    const float* hrow = H + (size_t)(i0 + col) * FDIM + quad * 8;

    #pragma unroll
    for (int kb = 0; kb < FDIM; kb += 32) {
        f32x4 h0 = *(const f32x4*)(hrow + kb);       // A[m=lane&15][k=quad*8+j]
        f32x4 h1 = *(const f32x4*)(hrow + kb + 4);
        short8 afr, b0, b1, b2, b3;
        #pragma unroll
        for (int j = 0; j < 4; ++j) {
            afr[j]     = (short)f2bf(h0[j]);
            afr[4 + j] = (short)f2bf(h1[j]);
        }
        #pragma unroll
        for (int j = 0; j < 8; ++j) {                // W tiny, L1-hot
            int k = kb + quad * 8 + j;
            b0[j] = (short)f2bf(W[k * UDIM + col]);
            b1[j] = (short)f2bf(W[k * UDIM + 16 + col]);
            b2[j] = (short)f2bf(W[k * UDIM + 32 + col]);
            b3[j] = (short)f2bf(W[k * UDIM + 48 + col]);
        }
        acc0 = __builtin_amdgcn_mfma_f32_16x16x32_bf16(afr, b0, acc0, 0, 0, 0);
        acc1 = __builtin_amdgcn_mfma_f32_16x16x32_bf16(afr, b1, acc1, 0, 0, 0);
        acc2 = __builtin_amdgcn_mfma_f32_16x16x32_bf16(afr, b2, acc2, 0, 0, 0);
        acc3 = __builtin_amdgcn_mfma_f32_16x16x32_bf16(afr, b3, acc3, 0, 0, 0);
    }
    #pragma unroll
    for (int r = 0; r < 4; ++r) {   // C/D: col(u)=lane&15 (+16/group), row=quad*4+r
        Xl[wave][quad * 4 + r][col]      = acc0[r];
        Xl[wave][quad * 4 + r][16 + col] = acc1[r];
        Xl[wave][quad * 4 + r][32 + col] = acc2[r];
        Xl[wave][quad * 4 + r][48 + col] = acc3[r];
    }
    __syncthreads();

    const int b = i0 >> 12, n0 = i0 & (NTOK - 1);
    float ps = 0.f, pt = 0.f;
    #pragma unroll
    for (int ui = 0; ui < 16; ++ui) {
        int u = quad * 16 + ui;
        float x = Xl[wave][col][u];
        ps = fmaf(x, a1[u], ps);
        pt = fmaf(x, a2[u], pt);
    }
    ps += __shfl_xor(ps, 16, 64); ps += __shfl_xor(ps, 32, 64);
    pt += __shfl_xor(pt, 16, 64); pt += __shfl_xor(pt, 32, 64);
    const float LOG2E = 1.44269504f;
    if (quad == 0) s_out[i0 + col] = ps * LOG2E;   // exp2 domain
    if (quad == 1) t_out[i0 + col] = pt * LOG2E;

    #pragma unroll
    for (int ui = 0; ui < 16; ++ui) {
        int u = quad * 16 + ui;
        XT[(size_t)(b * UDIM + u) * NTOK + n0 + col] = f2bf(Xl[wave][col][u]);
    }
}

// ---------------- kernel 2: fused mask+softmax+PV ---------------------------
// grid 512 = 8 batches x 64 row-tiles-of-64 (b = bx&7), 4 waves/block.
// Wave w owns rows [i0+w*16, +16) across the FULL k range. A[64][BK] f32 and
// XT[64][BK] bf16 staged per chunk via coalesced block-cooperative loads into
// double-buffered padded LDS; one __syncthreads per chunk.
__global__ __launch_bounds__(256) void attn_kernel(
    const float* __restrict__ A,            // f32 [B, N, N] -- 512 MB stream
    const unsigned short* __restrict__ XT,  // bf16 [B, 64, N]
    const float* __restrict__ s_in,         // log2e-scaled
    const float* __restrict__ t_in,         // log2e-scaled
    float* __restrict__ out)                // f32 [B, N, 64]
{
    __shared__ __align__(16) float          As[2][64][BK + 4];  // 34.8 KB
    __shared__ __align__(16) unsigned short Xs[2][64][BK + 8];  // 18.4 KB

    const int tid  = threadIdx.x;
    const int wave = tid >> 6, lane = tid & 63;
    const int col  = lane & 15, quad = lane >> 4;
    const int b    = blockIdx.x & 7;
    const int i0   = (blockIdx.x >> 3) * 64;

    // staging assignment: A -> 4 instrs, each 16 rows x 256 B (4x256B segs/wave)
    //                     XT -> 2 instrs, each 32 rows x 128 B
    const int arow = tid >> 4, acol = (tid & 15) * 4;
    const int xrow = tid >> 3, xcol = (tid & 7) * 8;
    const float* agp = A + ((size_t)(b * NTOK + i0 + arow)) * NTOK + acol;
    const unsigned short* xgp = XT + ((size_t)(b * UDIM + xrow)) * NTOK + xcol;

    const float s_m = s_in[b * NTOK + i0 + wave * 16 + col];
    const float* tbase = t_in + b * NTOK;

    f32x4 acc[4];
    #pragma unroll
    for (int f = 0; f < 4; ++f) acc[f] = (f32x4){0,0,0,0};
    float den = 0.f;

    f32x4 av[4], xv[2];

    // prologue: stage chunk 0
    #pragma unroll
    for (int i = 0; i < 4; ++i)
        av[i] = __builtin_nontemporal_load((const f32x4*)(agp + (size_t)i * 16 * NTOK));
    #pragma unroll
    for (int i = 0; i < 2; ++i)
        xv[i] = *(const f32x4*)(xgp + (size_t)i * 32 * NTOK);
    #pragma unroll
    for (int i = 0; i < 4; ++i) *(f32x4*)&As[0][arow + i * 16][acol] = av[i];
    #pragma unroll
    for (int i = 0; i < 2; ++i) *(f32x4*)&Xs[0][xrow + i * 32][xcol] = xv[i];

    for (int c = 0; c < NTOK / BK; ++c) {
        const int buf = c & 1;
        if (c < NTOK / BK - 1) {         // issue next-chunk loads (land under compute)
            const float* ag = agp + (c + 1) * BK;
            const unsigned short* xg = xgp + (c + 1) * BK;
            #pragma unroll
            for (int i = 0; i < 4; ++i)
                av[i] = __builtin_nontemporal_load((const f32x4*)(ag + (size_t)i * 16 * NTOK));
            #pragma unroll
            for (int i = 0; i < 2; ++i)
                xv[i] = *(const f32x4*)(xg + (size_t)i * 32 * NTOK);
        }
        __syncthreads();                 // buf's ds_writes visible; prev reads done

        #pragma unroll
        for (int ks = 0; ks < 2; ++ks) {
            const float* ar = &As[buf][wave * 16 + col][ks * 32 + quad * 8];
            f32x4 a0 = *(const f32x4*)ar;
            f32x4 a1 = *(const f32x4*)(ar + 4);
            const float* tp = tbase + c * BK + ks * 32 + quad * 8;
            f32x4 t0 = *(const f32x4*)tp;
            f32x4 t1 = *(const f32x4*)(tp + 4);

            unsigned uw[8];
            #pragma unroll
            for (int j = 0; j < 4; ++j) {
                float l0 = s_m + t0[j], l1 = s_m + t1[j];
                float e0 = fmaxf(l0, 0.2f * l0);   // lrelu commutes with log2e>0
                float e1 = fmaxf(l1, 0.2f * l1);
                float w0 = __builtin_amdgcn_exp2f(e0) * a0[j];  // masked -> exact 0
                float w1 = __builtin_amdgcn_exp2f(e1) * a1[j];
                den += w0 + w1;
                uw[j]     = __float_as_uint(w0) + 0x8000u;  // round-half-up bf16
                uw[4 + j] = __float_as_uint(w1) + 0x8000u;
            }
            PackU p;   // pack hi16 pairs: afr[k]=w(k), k=quad*8+j
            p.u[0] = __builtin_amdgcn_perm(uw[1], uw[0], 0x07060302u);
            p.u[1] = __builtin_amdgcn_perm(uw[3], uw[2], 0x07060302u);
            p.u[2] = __builtin_amdgcn_perm(uw[5], uw[4], 0x07060302u);
            p.u[3] = __builtin_amdgcn_perm(uw[7], uw[6], 0x07060302u);

            short8 bf0 = *(const short8*)&Xs[buf][col]     [ks * 32 + quad * 8];
            short8 bf1 = *(const short8*)&Xs[buf][16 + col][ks * 32 + quad * 8];
            short8 bf2 = *(const short8*)&Xs[buf][32 + col][ks * 32 + quad * 8];
            short8 bf3 = *(const short8*)&Xs[buf][48 + col][ks * 32 + quad * 8];

            acc[0] = __builtin_amdgcn_mfma_f32_16x16x32_bf16(p.s, bf0, acc[0], 0, 0, 0);
            acc[1] = __builtin_amdgcn_mfma_f32_16x16x32_bf16(p.s, bf1, acc[1], 0, 0, 0);
            acc[2] = __builtin_amdgcn_mfma_f32_16x16x32_bf16(p.s, bf2, acc[2], 0, 0, 0);
            acc[3] = __builtin_amdgcn_mfma_f32_16x16x32_bf16(p.s, bf3, acc[3], 0, 0, 0);
        }

        if (c < NTOK / BK - 1) {         // write next chunk into the other buffer
            const int nb = buf ^ 1;
            #pragma unroll
            for (int i = 0; i < 4; ++i) *(f32x4*)&As[nb][arow + i * 16][acol] = av[i];
            #pragma unroll
            for (int i = 0; i < 2; ++i) *(f32x4*)&Xs[nb][xrow + i * 32][xcol] = xv[i];
        }
    }

    // epilogue: den lives at lane with col==row; gather, divide, relu, store
    den += __shfl_xor(den, 16, 64);
    den += __shfl_xor(den, 32, 64);      // full row-den at every quad, keyed by col
    #pragma unroll
    for (int r = 0; r < 4; ++r) {
        float dd = __shfl(den, quad * 4 + r, 64);     // den of D-row quad*4+r
        const int row = i0 + wave * 16 + quad * 4 + r;
        #pragma unroll
        for (int f = 0; f < 4; ++f) {
            float o = fmaxf(acc[f][r] / dd, 0.f);
            __builtin_nontemporal_store(o, &out[(size_t)(b * NTOK + row) * UDIM + f * 16 + col]);
        }
    }
}

extern "C" void kernel_launch(void* const* d_in, const int* in_sizes, int n_in,
                              void* d_out, int out_size, void* d_ws, size_t ws_size,
                              hipStream_t stream) {
    const float* H  = (const float*)d_in[0];
    const float* A  = (const float*)d_in[1];
    const float* W  = (const float*)d_in[2];
    const float* a1 = (const float*)d_in[3];
    const float* a2 = (const float*)d_in[4];
    float* out = (float*)d_out;

    char* ws = (char*)d_ws;
    unsigned short* XT = (unsigned short*)ws;                               // 4 MB bf16
    size_t off = (size_t)BATCH * UDIM * NTOK * 2;
    float* s = (float*)(ws + off);                                          // 128 KB
    off += (size_t)BATCH * NTOK * 4;
    float* t = (float*)(ws + off);                                          // 128 KB

    prep_kernel<<<512, 256, 0, stream>>>(H, W, a1, a2, XT, s, t);
    attn_kernel<<<512, 256, 0, stream>>>(A, XT, s, t, out);
}